// Round 1
// baseline (16645.540 us; speedup 1.0000x reference)
//
#include <hip/hip_runtime.h>

// ---------------------------------------------------------------------------
// LexicalizedGrammarDecoder: encoder LSTM (128 steps) + init MLPs + attention
// precompute + decoder LSTM w/ attention (64 steps). bf16 MFMA everywhere.
// ---------------------------------------------------------------------------

constexpr int B_ = 128, S_ = 128, T_ = 64, H_ = 1024;
constexpr int KE_ = 1344;  // enc step K: 320 (emb pad) + 1024 (h)
constexpr int KD_ = 1920;  // dec step K: 576 (ans pad) + 320 (ctx pad) + 1024 (h)

using bf16x8 = __attribute__((ext_vector_type(8))) __bf16;
using f32x4  = __attribute__((ext_vector_type(4))) float;

__device__ __forceinline__ float ldf(const void* p, size_t i, bool bf) {
  return bf ? (float)((const __bf16*)p)[i] : ((const float*)p)[i];
}
__device__ __forceinline__ float sigf(float x) { return 1.f / (1.f + __expf(-x)); }
__device__ __forceinline__ float tanf_(float x) { return 1.f - 2.f / (1.f + __expf(2.f * x)); }

// --- dtype sniffer: are float inputs delivered as bf16? ---------------------
// Reading a true-f32 buffer as u16: even-indexed halves are random mantissa
// bits -> bf16-exponent uniform -> mostly garbage magnitudes. True bf16
// N(0,1) data is always in a sane magnitude range.
__global__ void sniff(const void* __restrict__ lex, int* __restrict__ flag) {
  if (threadIdx.x == 0 && blockIdx.x == 0) {
    const unsigned short* u = (const unsigned short*)lex;
    int garbage = 0;
    for (int i = 0; i < 64; ++i) {
      unsigned short v = u[1000000 + 2 * i];
      int ex = (v >> 7) & 0xFF;
      bool sane = ((v & 0x7FFF) == 0) || (ex >= 107 && ex <= 147);  // ~2^-20..2^20
      if (!sane) ++garbage;
    }
    *flag = (garbage >= 16) ? 0 : 1;  // 1 => inputs are bf16
  }
}

__global__ void cvt_to_f32(const void* __restrict__ src, float* __restrict__ dst,
                           int n, const int* __restrict__ flag) {
  int i = blockIdx.x * blockDim.x + threadIdx.x;
  bool bf = *flag != 0;
  if (i < n) dst[i] = ldf(src, i, bf);
}

__global__ void f2b(const float* __restrict__ s, __bf16* __restrict__ d, int n) {
  int i = blockIdx.x * blockDim.x + threadIdx.x;
  if (i < n) d[i] = (__bf16)s[i];
}

__global__ void zero_state(__bf16* __restrict__ h, float* __restrict__ c) {
  int i = blockIdx.x * blockDim.x + threadIdx.x;
  if (i < B_ * H_) { h[i] = (__bf16)0.f; c[i] = 0.f; }
}

// --- gate-reordered step-weight builders ------------------------------------
// new row n' = 64*(j>>4) + 16*g + (j&15), original row r = g*1024 + j.
// A 64-wide n'-strip gives one wave 4 MFMA tiles = gates i,f,g,o for 16 units.
__global__ void build_w_enc(const void* __restrict__ Wih, const void* __restrict__ Whh,
                            const void* __restrict__ bsrc, __bf16* __restrict__ W,
                            float* __restrict__ bias, const int* __restrict__ flag) {
  int np = blockIdx.x;
  int strip = np >> 6, rem = np & 63, g = rem >> 4, jj = rem & 15;
  int r = g * 1024 + strip * 16 + jj;
  bool bf = *flag != 0;
  for (int k = threadIdx.x; k < KE_; k += blockDim.x) {
    float v;
    if (k < 320) v = (k < 300) ? ldf(Wih, (size_t)r * 300 + k, bf) : 0.f;
    else         v = ldf(Whh, (size_t)r * 1024 + (k - 320), bf);
    W[(size_t)np * KE_ + k] = (__bf16)v;
  }
  if (threadIdx.x == 0) bias[np] = ldf(bsrc, r, bf);
}

__global__ void build_w_dec(const void* __restrict__ Wih, const void* __restrict__ Whh,
                            const void* __restrict__ bsrc, __bf16* __restrict__ W,
                            float* __restrict__ bias, const int* __restrict__ flag) {
  int np = blockIdx.x;
  int strip = np >> 6, rem = np & 63, g = rem >> 4, jj = rem & 15;
  int r = g * 1024 + strip * 16 + jj;
  bool bf = *flag != 0;
  for (int k = threadIdx.x; k < KD_; k += blockDim.x) {
    float v;
    if (k < 576)      v = (k < 556) ? ldf(Wih, (size_t)r * 856 + k, bf) : 0.f;
    else if (k < 896) v = ((k - 576) < 300) ? ldf(Wih, (size_t)r * 856 + 556 + (k - 576), bf) : 0.f;
    else              v = ldf(Whh, (size_t)r * 1024 + (k - 896), bf);
    W[(size_t)np * KD_ + k] = (__bf16)v;
  }
  if (threadIdx.x == 0) bias[np] = ldf(bsrc, r, bf);
}

// generic N-padded, K-exact fp->bf16 weight copy (rows >= N become zero)
__global__ void pad_cvt(const void* __restrict__ src, __bf16* __restrict__ dst,
                        int N, int K, int Kpad, const int* __restrict__ flag) {
  int n = blockIdx.x;
  bool bf = *flag != 0;
  for (int k = threadIdx.x; k < Kpad; k += blockDim.x) {
    float v = (n < N && k < K) ? ldf(src, (size_t)n * K + k, bf) : 0.f;
    dst[(size_t)n * Kpad + k] = (__bf16)v;
  }
}

// --- embedding gathers (padded to mult-of-32 K regions) ---------------------
__global__ void gather_emb(const void* __restrict__ lex, const int* __restrict__ seq,
                           __bf16* __restrict__ dst, const int* __restrict__ flag) {
  int blk = blockIdx.x;          // blk = t*B + b
  int t = blk >> 7, b = blk & 127;
  int id = seq[b * S_ + t];
  bool bf = *flag != 0;
  for (int k = threadIdx.x; k < 320; k += blockDim.x) {
    float v = (k < 300) ? ldf(lex, (size_t)id * 300 + k, bf) : 0.f;
    dst[(size_t)blk * 320 + k] = (__bf16)v;
  }
}

__global__ void gather_ans(const void* __restrict__ nt, const void* __restrict__ lex,
                           const int* __restrict__ trg, const int* __restrict__ par,
                           const int* __restrict__ plex, __bf16* __restrict__ dst,
                           const int* __restrict__ flag) {
  int blk = blockIdx.x;          // blk = t*B + b
  int t = blk >> 7, b = blk & 127;
  int i1 = trg[b * T_ + t], i2 = par[b * T_ + t], i3 = plex[b * T_ + t];
  bool bf = *flag != 0;
  for (int k = threadIdx.x; k < 576; k += blockDim.x) {
    float v = 0.f;
    if (k < 128)      v = ldf(nt, (size_t)i1 * 128 + k, bf);
    else if (k < 256) v = ldf(nt, (size_t)i2 * 128 + (k - 128), bf);
    else if (k < 556) v = ldf(lex, (size_t)i3 * 300 + (k - 256), bf);
    dst[(size_t)blk * 576 + k] = (__bf16)v;
  }
}

// --- fused LSTM step: z = [A0|A1|A2] @ W'^T + b, gates, state update --------
// grid (64 strips, 2 m-halves) x 256 thr. Wave = 16 batch rows x 16 hidden
// units (4 gate tiles). MFMA layouts per guide (m89/m91 verified).
template <bool ENC>
__global__ __launch_bounds__(256)
void lstm_step(const __bf16* __restrict__ A0, int L0, int ld0,
               const __bf16* __restrict__ A1, int L1, int ld1,
               const __bf16* __restrict__ A2, int ld2,
               const __bf16* __restrict__ W, int Ktot,
               const float* __restrict__ bias,
               const __bf16* __restrict__ hRead, __bf16* __restrict__ hWrite,
               float* __restrict__ cState,
               const int* __restrict__ lens, int t,
               __bf16* __restrict__ shOut,
               void* __restrict__ out, const int* __restrict__ flag) {
  const int lane = threadIdx.x & 63;
  const int wave = threadIdx.x >> 6;
  const int strip = blockIdx.x;
  const int m0 = blockIdx.y * 64 + wave * 16;
  const int col = lane & 15;
  const int quad = lane >> 4;
  const int koff = quad * 8;

  f32x4 acc0 = {0.f, 0.f, 0.f, 0.f};
  f32x4 acc1 = acc0, acc2 = acc0, acc3 = acc0;
  const int am = m0 + col;
  const __bf16* wb = W + (size_t)(strip * 64 + col) * Ktot + koff;

  for (int k0 = 0; k0 < Ktot; k0 += 32) {
    const __bf16* ap;
    if (k0 < L0)           ap = A0 + (size_t)am * ld0 + k0;
    else if (k0 < L0 + L1) ap = A1 + (size_t)am * ld1 + (k0 - L0);
    else                   ap = A2 + (size_t)am * ld2 + (k0 - L0 - L1);
    bf16x8 af = *(const bf16x8*)(ap + koff);
    bf16x8 b0 = *(const bf16x8*)(wb + (size_t)0 * 16 * Ktot + k0);
    bf16x8 b1 = *(const bf16x8*)(wb + (size_t)1 * 16 * Ktot + k0);
    bf16x8 b2 = *(const bf16x8*)(wb + (size_t)2 * 16 * Ktot + k0);
    bf16x8 b3 = *(const bf16x8*)(wb + (size_t)3 * 16 * Ktot + k0);
    acc0 = __builtin_amdgcn_mfma_f32_16x16x32_bf16(af, b0, acc0, 0, 0, 0);
    acc1 = __builtin_amdgcn_mfma_f32_16x16x32_bf16(af, b1, acc1, 0, 0, 0);
    acc2 = __builtin_amdgcn_mfma_f32_16x16x32_bf16(af, b2, acc2, 0, 0, 0);
    acc3 = __builtin_amdgcn_mfma_f32_16x16x32_bf16(af, b3, acc3, 0, 0, 0);
  }

  const int j = strip * 16 + col;
  const float bi = bias[strip * 64 + 0 + col];
  const float bf_ = bias[strip * 64 + 16 + col];
  const float bg = bias[strip * 64 + 32 + col];
  const float bo = bias[strip * 64 + 48 + col];
  const bool obf = *flag != 0;

#pragma unroll
  for (int r = 0; r < 4; ++r) {
    int m = m0 + quad * 4 + r;
    float ig = sigf(acc0[r] + bi);
    float fg = sigf(acc1[r] + bf_);
    float gg = tanf_(acc2[r] + bg);
    float og = sigf(acc3[r] + bo);
    size_t sidx = (size_t)m * H_ + j;
    float cOld = cState[sidx];
    float c2 = fg * cOld + ig * gg;
    float h2 = og * tanf_(c2);
    if (ENC) {
      bool valid = t < lens[m];
      cState[sidx] = valid ? c2 : cOld;
      hWrite[sidx] = valid ? (__bf16)h2 : hRead[sidx];
      shOut[((size_t)m * S_ + t) * H_ + j] = valid ? (__bf16)h2 : (__bf16)0.f;
    } else {
      cState[sidx] = c2;
      hWrite[sidx] = (__bf16)h2;
      size_t oidx = ((size_t)m * T_ + t) * H_ + j;
      if (obf) ((__bf16*)out)[oidx] = (__bf16)h2;
      else     ((float*)out)[oidx] = h2;
    }
  }
}

// --- generic GEMM: C = act(A @ W^T + bias), one 16x16 tile per wave ---------
template <int ACT, bool WB, bool WF>
__global__ __launch_bounds__(256)
void gemm16(const __bf16* __restrict__ A, int lda,
            const __bf16* __restrict__ W, int K,
            const float* __restrict__ bias, int Nreal,
            __bf16* __restrict__ Cb, float* __restrict__ Cf, int ldc) {
  const int lane = threadIdx.x & 63;
  const int wave = threadIdx.x >> 6;
  const int col = lane & 15, quad = lane >> 4, koff = quad * 8;
  const int n0 = blockIdx.x * 16;
  const int m0 = blockIdx.y * 64 + wave * 16;
  f32x4 acc = {0.f, 0.f, 0.f, 0.f};
  const __bf16* ap = A + (size_t)(m0 + col) * lda + koff;
  const __bf16* wp = W + (size_t)(n0 + col) * K + koff;
  for (int k0 = 0; k0 < K; k0 += 32) {
    bf16x8 af = *(const bf16x8*)(ap + k0);
    bf16x8 bf = *(const bf16x8*)(wp + k0);
    acc = __builtin_amdgcn_mfma_f32_16x16x32_bf16(af, bf, acc, 0, 0, 0);
  }
  int n = n0 + col;
  float bv = (n < Nreal) ? bias[n] : 0.f;
#pragma unroll
  for (int r = 0; r < 4; ++r) {
    int m = m0 + quad * 4 + r;
    float v = acc[r] + bv;
    if (ACT == 1) v = fmaxf(v, 0.f);
    if (ACT == 2) v = tanf_(v);
    size_t idx = (size_t)m * ldc + n;
    if (WB) Cb[idx] = (__bf16)v;
    if (WF) Cf[idx] = v;
  }
}

// --- per-step attention: a_key, masked softmax, context ---------------------
__global__ __launch_bounds__(256)
void attention(const __bf16* __restrict__ hD,
               const float* __restrict__ qkey, const float* __restrict__ qval,
               const float* __restrict__ Wa, const float* __restrict__ ba,
               const int* __restrict__ lens, __bf16* __restrict__ ctx) {
  __shared__ float hs[H_];
  __shared__ float qk[S_ * 101];  // stride 101: conflict-free
  __shared__ float ak[112];
  __shared__ float wts[S_];
  __shared__ float sc[S_];
  const int b = blockIdx.x, tid = threadIdx.x;
  for (int k = tid; k < H_; k += 256) hs[k] = (float)hD[(size_t)b * H_ + k];
  for (int i = tid; i < S_ * 100; i += 256) {
    int s = i / 100, k = i - s * 100;
    qk[s * 101 + k] = qkey[((size_t)b * S_ + s) * 112 + k];
  }
  __syncthreads();
  const int wave = tid >> 6, lane = tid & 63;
  for (int n = wave; n < 100; n += 4) {
    float acc = 0.f;
    for (int k = lane; k < H_; k += 64) acc += hs[k] * Wa[(size_t)n * H_ + k];
#pragma unroll
    for (int off = 32; off > 0; off >>= 1) acc += __shfl_down(acc, off);
    if (lane == 0) ak[n] = tanf_(acc + ba[n]);
  }
  __syncthreads();
  int len = lens[b];
  float e = -1e30f;
  if (tid < S_ && tid < len) {
    float acc = 0.f;
#pragma unroll 4
    for (int k = 0; k < 100; ++k) acc += qk[tid * 101 + k] * ak[k];
    e = acc;
  }
  if (tid < S_) { wts[tid] = e; sc[tid] = e; }
  __syncthreads();
  for (int off = 64; off > 0; off >>= 1) {
    if (tid < off) sc[tid] = fmaxf(sc[tid], sc[tid + off]);
    __syncthreads();
  }
  float mx = sc[0];
  __syncthreads();
  if (tid < S_) {
    float ex = (wts[tid] <= -1e29f) ? 0.f : __expf(wts[tid] - mx);
    wts[tid] = ex; sc[tid] = ex;
  }
  __syncthreads();
  for (int off = 64; off > 0; off >>= 1) {
    if (tid < off) sc[tid] += sc[tid + off];
    __syncthreads();
  }
  float inv = 1.f / sc[0];
  for (int d = tid; d < 320; d += 256) {
    float v = 0.f;
    if (d < 300) {
      for (int s = 0; s < S_; ++s) v += wts[s] * qval[((size_t)b * S_ + s) * 304 + d];
      v *= inv;
    }
    ctx[(size_t)b * 320 + d] = (__bf16)v;
  }
}

// ---------------------------------------------------------------------------
extern "C" void kernel_launch(void* const* d_in, const int* in_sizes, int n_in,
                              void* d_out, int out_size, void* d_ws, size_t ws_size,
                              hipStream_t stream) {
  const int* src_seqs = (const int*)d_in[0];
  const int* src_len  = (const int*)d_in[1];
  const int* trg_nt   = (const int*)d_in[2];
  const int* par_nt   = (const int*)d_in[3];
  const int* par_lex  = (const int*)d_in[4];
  const void* lex_emb = d_in[5];
  const void* nt_emb  = d_in[6];
  const void* encWih  = d_in[7];
  const void* encWhh  = d_in[8];
  const void* encB    = d_in[9];
  const void* decWih  = d_in[10];
  const void* decWhh  = d_in[11];
  const void* decB    = d_in[12];
  const void* Wh1 = d_in[13]; const void* bh1 = d_in[14];
  const void* Wh2 = d_in[15]; const void* bh2 = d_in[16];
  const void* Wc1 = d_in[17]; const void* bc1 = d_in[18];
  const void* Wc2 = d_in[19]; const void* bc2 = d_in[20];
  const void* Wa  = d_in[21]; const void* ba  = d_in[22];
  const void* Wqk = d_in[23]; const void* bqk = d_in[24];
  const void* Wqv = d_in[25]; const void* bqv = d_in[26];

  char* base = (char*)d_ws;
  size_t off = 0;
  auto alloc = [&](size_t bytes) -> char* {
    char* p = base + off;
    off += (bytes + 255) & ~(size_t)255;
    return p;
  };
  __bf16* wEnc = (__bf16*)alloc((size_t)4096 * KE_ * 2);
  float*  bEnc = (float*)alloc(4096 * 4);
  __bf16* wDec = (__bf16*)alloc((size_t)4096 * KD_ * 2);
  float*  bDec = (float*)alloc(4096 * 4);
  __bf16* embE = (__bf16*)alloc((size_t)S_ * B_ * 320 * 2);
  __bf16* ansP = (__bf16*)alloc((size_t)T_ * B_ * 576 * 2);
  __bf16* SH   = (__bf16*)alloc((size_t)B_ * S_ * H_ * 2);
  __bf16* wh1p = (__bf16*)alloc((size_t)2048 * 1024 * 2);
  __bf16* wh2p = (__bf16*)alloc((size_t)1024 * 2048 * 2);
  __bf16* wc1p = (__bf16*)alloc((size_t)2048 * 1024 * 2);
  __bf16* wc2p = (__bf16*)alloc((size_t)1024 * 2048 * 2);
  __bf16* wqkp = (__bf16*)alloc((size_t)112 * 1024 * 2);
  __bf16* wqvp = (__bf16*)alloc((size_t)304 * 1024 * 2);
  float*  qkey = (float*)alloc((size_t)B_ * S_ * 112 * 4);
  float*  qval = (float*)alloc((size_t)B_ * S_ * 304 * 4);
  __bf16* hE0 = (__bf16*)alloc((size_t)B_ * H_ * 2);
  __bf16* hE1 = (__bf16*)alloc((size_t)B_ * H_ * 2);
  __bf16* hE[2] = {hE0, hE1};
  float*  cE  = (float*)alloc((size_t)B_ * H_ * 4);
  __bf16* cEb = (__bf16*)alloc((size_t)B_ * H_ * 2);
  __bf16* t1b = (__bf16*)alloc((size_t)B_ * 2048 * 2);
  __bf16* t2b = (__bf16*)alloc((size_t)B_ * 2048 * 2);
  __bf16* hD0 = (__bf16*)alloc((size_t)B_ * H_ * 2);
  __bf16* hD1 = (__bf16*)alloc((size_t)B_ * H_ * 2);
  __bf16* hD[2] = {hD0, hD1};
  float*  cD  = (float*)alloc((size_t)B_ * H_ * 4);
  __bf16* ctx = (__bf16*)alloc((size_t)B_ * 320 * 2);
  float*  waF  = (float*)alloc((size_t)100 * 1024 * 4);
  float*  bh1F = (float*)alloc(2048 * 4);
  float*  bh2F = (float*)alloc(1024 * 4);
  float*  bc1F = (float*)alloc(2048 * 4);
  float*  bc2F = (float*)alloc(1024 * 4);
  float*  baF  = (float*)alloc(112 * 4);
  float*  bqkF = (float*)alloc(112 * 4);
  float*  bqvF = (float*)alloc(304 * 4);
  int*    flag = (int*)alloc(256);
  if (off > ws_size) return;  // workspace too small: bail (visible as failure)

  // ---- prep ----
  sniff<<<1, 64, 0, stream>>>(lex_emb, flag);
  cvt_to_f32<<<400, 256, 0, stream>>>(Wa, waF, 102400, flag);
  cvt_to_f32<<<8, 256, 0, stream>>>(bh1, bh1F, 2048, flag);
  cvt_to_f32<<<4, 256, 0, stream>>>(bh2, bh2F, 1024, flag);
  cvt_to_f32<<<8, 256, 0, stream>>>(bc1, bc1F, 2048, flag);
  cvt_to_f32<<<4, 256, 0, stream>>>(bc2, bc2F, 1024, flag);
  cvt_to_f32<<<1, 256, 0, stream>>>(ba, baF, 100, flag);
  cvt_to_f32<<<1, 256, 0, stream>>>(bqk, bqkF, 100, flag);
  cvt_to_f32<<<2, 256, 0, stream>>>(bqv, bqvF, 300, flag);
  build_w_enc<<<4096, 256, 0, stream>>>(encWih, encWhh, encB, wEnc, bEnc, flag);
  build_w_dec<<<4096, 256, 0, stream>>>(decWih, decWhh, decB, wDec, bDec, flag);
  pad_cvt<<<2048, 256, 0, stream>>>(Wh1, wh1p, 2048, 1024, 1024, flag);
  pad_cvt<<<1024, 256, 0, stream>>>(Wh2, wh2p, 1024, 2048, 2048, flag);
  pad_cvt<<<2048, 256, 0, stream>>>(Wc1, wc1p, 2048, 1024, 1024, flag);
  pad_cvt<<<1024, 256, 0, stream>>>(Wc2, wc2p, 1024, 2048, 2048, flag);
  pad_cvt<<<112, 256, 0, stream>>>(Wqk, wqkp, 100, 1024, 1024, flag);
  pad_cvt<<<304, 256, 0, stream>>>(Wqv, wqvp, 300, 1024, 1024, flag);
  gather_emb<<<S_ * B_, 256, 0, stream>>>(lex_emb, src_seqs, embE, flag);
  gather_ans<<<T_ * B_, 256, 0, stream>>>(nt_emb, lex_emb, trg_nt, par_nt, par_lex, ansP, flag);
  zero_state<<<512, 256, 0, stream>>>(hE[0], cE);

  // ---- encoder recurrence ----
  for (int t = 0; t < S_; ++t) {
    lstm_step<true><<<dim3(64, 2), 256, 0, stream>>>(
        embE + (size_t)t * B_ * 320, 320, 320,
        hE[t & 1], 1024, 1024,
        (const __bf16*)nullptr, 0,
        wEnc, KE_, bEnc,
        hE[t & 1], hE[(t + 1) & 1], cE,
        src_len, t, SH, nullptr, flag);
  }

  // ---- decoder init MLPs (final enc state lands in hE[0]/cE) ----
  f2b<<<512, 256, 0, stream>>>(cE, cEb, B_ * H_);
  gemm16<1, true, false><<<dim3(128, 2), 256, 0, stream>>>(hE[0], 1024, wh1p, 1024, bh1F, 2048, t1b, nullptr, 2048);
  gemm16<0, true, false><<<dim3(64, 2), 256, 0, stream>>>(t1b, 2048, wh2p, 2048, bh2F, 1024, hD[0], nullptr, 1024);
  gemm16<1, true, false><<<dim3(128, 2), 256, 0, stream>>>(cEb, 1024, wc1p, 1024, bc1F, 2048, t2b, nullptr, 2048);
  gemm16<0, false, true><<<dim3(64, 2), 256, 0, stream>>>(t2b, 2048, wc2p, 2048, bc2F, 1024, nullptr, cD, 1024);

  // ---- attention keys/values over all (b,s) ----
  gemm16<2, false, true><<<dim3(7, 256), 256, 0, stream>>>(SH, 1024, wqkp, 1024, bqkF, 100, nullptr, qkey, 112);
  gemm16<0, false, true><<<dim3(19, 256), 256, 0, stream>>>(SH, 1024, wqvp, 1024, bqvF, 300, nullptr, qval, 304);

  // ---- decoder recurrence ----
  for (int t = 0; t < T_; ++t) {
    attention<<<B_, 256, 0, stream>>>(hD[t & 1], qkey, qval, waF, baF, src_len, ctx);
    lstm_step<false><<<dim3(64, 2), 256, 0, stream>>>(
        ansP + (size_t)t * B_ * 576, 576, 576,
        ctx, 320, 320,
        hD[t & 1], 1024,
        wDec, KD_, bDec,
        hD[t & 1], hD[(t + 1) & 1], cD,
        nullptr, t, nullptr, d_out, flag);
  }
}